// Round 13
// baseline (778.310 us; speedup 1.0000x reference)
//
#include <hip/hip_runtime.h>
#include <hip/hip_bf16.h>

typedef __bf16 bf16x8 __attribute__((ext_vector_type(8)));
typedef float  f32x4  __attribute__((ext_vector_type(4)));
typedef unsigned short u16;

#define GLDS16(gsrc, ldst)                                                        \
  __builtin_amdgcn_global_load_lds(                                               \
      (const __attribute__((address_space(1))) unsigned int*)(gsrc),              \
      (__attribute__((address_space(3))) unsigned int*)(ldst), 16, 0, 0)

#define BAR() __builtin_amdgcn_s_barrier()
#define WAIT_LGKM0() asm volatile("s_waitcnt lgkmcnt(0)" ::: "memory")
#define WAIT_VM6() asm volatile("s_waitcnt vmcnt(6)" ::: "memory")

__device__ __forceinline__ u16 f2b(float f) {
  unsigned int u = __builtin_bit_cast(unsigned int, f);
  u = (u + 0x7fffu + ((u >> 16) & 1u)) >> 16;
  return (u16)u;
}
__device__ __forceinline__ float b2f(u16 b) {
  unsigned int u = ((unsigned int)b) << 16;
  return __builtin_bit_cast(float, u);
}

// ---------------- fp32 -> bf16 convert ----------------
__global__ __launch_bounds__(256) void cvt_kernel(const float4* __restrict__ in,
                                                  ushort4* __restrict__ out, int n4) {
  int i = blockIdx.x * blockDim.x + threadIdx.x;
  int stride = gridDim.x * blockDim.x;
  for (; i < n4; i += stride) {
    float4 v = in[i];
    ushort4 o;
    o.x = f2b(v.x); o.y = f2b(v.y); o.z = f2b(v.z); o.w = f2b(v.w);
    out[i] = o;
  }
}

// ------ LoRA rank-projection, wave-K-split: t_bf16[m][r] = 0.5*sum_k Xb[m][k]*A[r][k]
__global__ __launch_bounds__(256) void lora_t2(const u16* __restrict__ Xb, int K,
                                               const float* __restrict__ A1,
                                               const float* __restrict__ A2,
                                               const int* __restrict__ lidx,
                                               const int* __restrict__ layer,
                                               u16* __restrict__ t1,
                                               u16* __restrict__ t2) {
  __shared__ float red1[4][64][4];
  __shared__ float red2[4][64][4];
  const int lane = threadIdx.x & 63, wid = threadIdx.x >> 6;
  const int m0 = blockIdx.x * 16;
  const int li = lidx[m0 >> 9];
  const size_t abase = ((size_t)layer[0] * 16 + li) * 16 * (size_t)K;
  const int r = lane & 15, kg = lane >> 4;
  const int Kq = K >> 2, kb = wid * Kq;
  f32x4 acc1 = {0.f, 0.f, 0.f, 0.f}, acc2 = {0.f, 0.f, 0.f, 0.f};
  for (int k0 = kb; k0 < kb + Kq; k0 += 32) {
    bf16x8 a = *(const bf16x8*)&Xb[(size_t)(m0 + r) * K + k0 + kg * 8];
    const float* ap = A1 + abase + (size_t)r * K + k0 + kg * 8;
    float4 f0 = *(const float4*)ap;
    float4 f1 = *(const float4*)(ap + 4);
    bf16x8 b;
    b[0] = (__bf16)f0.x; b[1] = (__bf16)f0.y; b[2] = (__bf16)f0.z; b[3] = (__bf16)f0.w;
    b[4] = (__bf16)f1.x; b[5] = (__bf16)f1.y; b[6] = (__bf16)f1.z; b[7] = (__bf16)f1.w;
    acc1 = __builtin_amdgcn_mfma_f32_16x16x32_bf16(a, b, acc1, 0, 0, 0);
    if (A2) {
      const float* ap2 = A2 + abase + (size_t)r * K + k0 + kg * 8;
      float4 g0 = *(const float4*)ap2;
      float4 g1 = *(const float4*)(ap2 + 4);
      bf16x8 b2;
      b2[0] = (__bf16)g0.x; b2[1] = (__bf16)g0.y; b2[2] = (__bf16)g0.z; b2[3] = (__bf16)g0.w;
      b2[4] = (__bf16)g1.x; b2[5] = (__bf16)g1.y; b2[6] = (__bf16)g1.z; b2[7] = (__bf16)g1.w;
      acc2 = __builtin_amdgcn_mfma_f32_16x16x32_bf16(a, b2, acc2, 0, 0, 0);
    }
  }
#pragma unroll
  for (int j = 0; j < 4; ++j) {
    red1[wid][lane][j] = acc1[j];
    if (A2) red2[wid][lane][j] = acc2[j];
  }
  __syncthreads();
  if (wid == 0) {
#pragma unroll
    for (int j = 0; j < 4; ++j) {
      int m = m0 + kg * 4 + j;
      float v1 = red1[0][lane][j] + red1[1][lane][j] + red1[2][lane][j] + red1[3][lane][j];
      t1[(size_t)m * 16 + r] = f2b(0.5f * v1);
      if (A2) {
        float v2 = red2[0][lane][j] + red2[1][lane][j] + red2[2][lane][j] + red2[3][lane][j];
        t2[(size_t)m * 16 + r] = f2b(0.5f * v2);
      }
    }
  }
}

// ===================== shared 8-phase tile macros =====================
#define RD_A(dst, buf, mh) do {                                                \
    _Pragma("unroll")                                                          \
    for (int mf_ = 0; mf_ < 4; ++mf_)                                          \
      _Pragma("unroll")                                                        \
      for (int ks_ = 0; ks_ < 2; ++ks_) {                                      \
        int row_ = wm * 128 + (mh) * 64 + mf_ * 16 + lr;                       \
        int sl_ = (ks_ * 4 + kg) ^ rx;                                         \
        dst[mf_][ks_] = *(const bf16x8*)&sA[(buf) * 16384 + row_ * 64 + sl_ * 8]; \
      }                                                                        \
  } while (0)

#define RD_B(dst, buf, nh) do {                                                \
    _Pragma("unroll")                                                          \
    for (int nf_ = 0; nf_ < 2; ++nf_)                                          \
      _Pragma("unroll")                                                        \
      for (int ks_ = 0; ks_ < 2; ++ks_) {                                      \
        int row_ = wn * 64 + (nh) * 32 + nf_ * 16 + lr;                        \
        int sl_ = (ks_ * 4 + kg) ^ rx;                                         \
        dst[nf_][ks_] = *(const bf16x8*)&sB[(buf) * 16384 + row_ * 64 + sl_ * 8]; \
      }                                                                        \
  } while (0)

#define MMA_Q(AF, BF, mb, nb) do {                                             \
    __builtin_amdgcn_s_setprio(1);                                             \
    _Pragma("unroll")                                                          \
    for (int mf_ = 0; mf_ < 4; ++mf_)                                          \
      _Pragma("unroll")                                                        \
      for (int nf_ = 0; nf_ < 2; ++nf_)                                        \
        _Pragma("unroll")                                                      \
        for (int ks_ = 0; ks_ < 2; ++ks_)                                      \
          acc[(mb) + mf_][(nb) + nf_] = __builtin_amdgcn_mfma_f32_16x16x32_bf16( \
              AF[mf_][ks_], BF[nf_][ks_], acc[(mb) + mf_][(nb) + nf_], 0, 0, 0); \
    __builtin_amdgcn_s_setprio(0);                                             \
  } while (0)

// ================= 8-phase 256x256 fused gate|up GEMM (+Wd-cvt tail blocks) ====
// Deep-prefetch schedule: stages at g1:(1,1) g3:(0,2) g4:(0,3)+(0,0) g5:(0,1)
// g7:(1,2) g8:(1,3)+(1,0); counted vmcnt(6) at g4/g8 (3 half-tiles in flight).
#define STAGE(buf, half, kt) do {                                              \
    int r0_ = ((half) & 1) * 128;                                              \
    const u16* gs_ = ((half) < 2)                                              \
        ? (Xb + (size_t)(m0 + r0_) * 4096 + (size_t)(kt) * 64)                 \
        : (W + (size_t)(n0 + r0_) * 4096 + (size_t)(kt) * 64);                 \
    u16* ld_ = (((half) < 2) ? sA : sB) + (buf) * 16384 + r0_ * 64;            \
    _Pragma("unroll")                                                          \
    for (int i_ = 0; i_ < 2; ++i_) {                                           \
      int ub_ = (wid << 6) + i_ * 512;                                         \
      int un_ = ub_ + lane;                                                    \
      int ur_ = un_ >> 3, us_ = (un_ & 7) ^ (ur_ & 7);                         \
      GLDS16(gs_ + (size_t)ur_ * 4096 + us_ * 8, ld_ + ub_ * 8);               \
    }                                                                          \
  } while (0)

// Blocks 0..703: GEMM (8 m-tiles x 88 padded n-tiles, XCD-grouped by B-panel).
// Blocks 704..959: convert Wd fp32->bf16 into wdb3 (fills the GEMM tail wave).
__global__ __launch_bounds__(512, 2) void gemm_gup8(
    const u16* __restrict__ Xb, const u16* __restrict__ Wg, const u16* __restrict__ Wu,
    const u16* __restrict__ tg, const u16* __restrict__ tu,
    const float* __restrict__ Bg, const float* __restrict__ Bu,
    const int* __restrict__ lidx, const int* __restrict__ layer,
    u16* __restrict__ gout, u16* __restrict__ uout,
    const float4* __restrict__ Wdf, ushort4* __restrict__ wdb3) {
  constexpr int F = 11008;
  const int b = blockIdx.x;
  if (b >= 704) {  // Wd convert tail: 256 blocks, grid-stride over 11272192 float4
    int i = (b - 704) * 512 + threadIdx.x;
    for (; i < 11272192; i += 256 * 512) {
      float4 v = Wdf[i];
      ushort4 o;
      o.x = f2b(v.x); o.y = f2b(v.y); o.z = f2b(v.z); o.w = f2b(v.w);
      wdb3[i] = o;
    }
    return;
  }
  const int xcd = b & 7, j = b >> 3;
  const int ny = xcd + 8 * (j >> 3);
  const int mx = j & 7;
  if (ny >= 86) return;
  extern __shared__ u16 smem[];
  u16* sA = smem;            // [2][256*64]
  u16* sB = smem + 32768;    // [2][256*64]
  const int tid = threadIdx.x, lane = tid & 63, wid = tid >> 6;
  const int lr = lane & 15, kg = lane >> 4, rx = lr & 7;
  const int wm = wid >> 2, wn = wid & 3;
  const bool isUp = ny >= 43;
  const int m0 = mx * 256;
  const int n0 = (isUp ? ny - 43 : ny) * 256;
  const u16* W = isUp ? Wu : Wg;
  const u16* tb = isUp ? tu : tg;
  const float* Bw = isUp ? Bu : Bg;
  u16* ob = isUp ? uout : gout;

  f32x4 acc[8][4] = {};
  bf16x8 a0[4][2], a1[4][2], b0[2][2], b1[2][2];

  // prologue: tile0 all 4 halves -> buf0; tile1 (1,2),(1,3),(1,0) -> buf1
  STAGE(0, 0, 0); STAGE(0, 1, 0); STAGE(0, 2, 0); STAGE(0, 3, 0);
  STAGE(1, 2, 1); STAGE(1, 3, 1); STAGE(1, 0, 1);
  WAIT_VM6(); BAR();

#pragma unroll 1
  for (int u = 0; u < 32; ++u) {
    const int ktA = (2 * u + 1) & 63;
    const int kt0 = (2 * u + 2) & 63;
    const int kt1 = (2 * u + 3) & 63;
    // g1
    RD_A(a0, 0, 0); RD_B(b0, 0, 0);
    STAGE(1, 1, ktA);
    BAR(); WAIT_LGKM0();
    MMA_Q(a0, b0, 0, 0);
    BAR();
    // g2
    RD_B(b1, 0, 1);
    BAR(); WAIT_LGKM0();
    MMA_Q(a0, b1, 0, 2);
    BAR();
    // g3
    RD_A(a1, 0, 1);
    STAGE(0, 2, kt0);
    BAR(); WAIT_LGKM0();
    MMA_Q(a1, b1, 4, 2);
    BAR();
    // g4
    STAGE(0, 3, kt0); STAGE(0, 0, kt0);
    BAR();
    MMA_Q(a1, b0, 4, 0);
    WAIT_VM6();
    BAR();
    // g5
    RD_A(a0, 1, 0); RD_B(b0, 1, 0);
    STAGE(0, 1, kt0);
    BAR(); WAIT_LGKM0();
    MMA_Q(a0, b0, 0, 0);
    BAR();
    // g6
    RD_B(b1, 1, 1);
    BAR(); WAIT_LGKM0();
    MMA_Q(a0, b1, 0, 2);
    BAR();
    // g7
    RD_A(a1, 1, 1);
    STAGE(1, 2, kt1);
    BAR(); WAIT_LGKM0();
    MMA_Q(a1, b1, 4, 2);
    BAR();
    // g8
    STAGE(1, 3, kt1); STAGE(1, 0, kt1);
    BAR();
    MMA_Q(a1, b0, 4, 0);
    WAIT_VM6();
    BAR();
  }

  // ---- LoRA via MFMA (K=16 padded to 32), then bf16 store ----
  const int li = lidx[m0 >> 9];
  const size_t bbase = ((size_t)layer[0] * 16 + li) * (size_t)F * 16;
  bf16x8 la[8], lb[4];
  const bf16x8 zz = {};
#pragma unroll
  for (int mf = 0; mf < 8; ++mf) {
    int row = m0 + wm * 128 + mf * 16 + lr;
    la[mf] = (kg < 2) ? *(const bf16x8*)&tb[(size_t)row * 16 + kg * 8] : zz;
  }
#pragma unroll
  for (int nf = 0; nf < 4; ++nf) {
    int col = n0 + wn * 64 + nf * 16 + lr;
    if (kg < 2) {
      const float* bp = Bw + bbase + (size_t)col * 16 + kg * 8;
      float4 f0 = *(const float4*)bp;
      float4 f1 = *(const float4*)(bp + 4);
      bf16x8 v;
      v[0] = (__bf16)f0.x; v[1] = (__bf16)f0.y; v[2] = (__bf16)f0.z; v[3] = (__bf16)f0.w;
      v[4] = (__bf16)f1.x; v[5] = (__bf16)f1.y; v[6] = (__bf16)f1.z; v[7] = (__bf16)f1.w;
      lb[nf] = v;
    } else lb[nf] = zz;
  }
#pragma unroll
  for (int mf = 0; mf < 8; ++mf)
#pragma unroll
    for (int nf = 0; nf < 4; ++nf)
      acc[mf][nf] = __builtin_amdgcn_mfma_f32_16x16x32_bf16(la[mf], lb[nf], acc[mf][nf], 0, 0, 0);

#pragma unroll
  for (int mf = 0; mf < 8; ++mf)
#pragma unroll
    for (int nf = 0; nf < 4; ++nf)
#pragma unroll
      for (int j2 = 0; j2 < 4; ++j2) {
        int row = m0 + wm * 128 + mf * 16 + kg * 4 + j2;
        int col = n0 + wn * 64 + nf * 16 + lr;
        ob[(size_t)row * F + col] = f2b(acc[mf][nf][j2]);
      }
}

// ====== 8-phase 256x256 down GEMM, K-split=2 over 172 tiles, fp32 partials =====
// Same deep-prefetch schedule. z in {0,1}; z==0 folds the down-LoRA via MFMA.
#define STAGE_D(buf, half, kt) do {                                           \
    int r0_ = ((half) & 1) * 128;                                             \
    const u16* gs_ = ((half) < 2)                                             \
        ? (Ab + (size_t)(m0 + r0_) * 11008 + (size_t)(kt) * 64)               \
        : (Wd + (size_t)(n0 + r0_) * 11008 + (size_t)(kt) * 64);              \
    u16* ld_ = (((half) < 2) ? sA : sB) + (buf) * 16384 + r0_ * 64;           \
    _Pragma("unroll")                                                         \
    for (int i_ = 0; i_ < 2; ++i_) {                                          \
      int ub_ = (wid << 6) + i_ * 512;                                        \
      int un_ = ub_ + lane;                                                   \
      int ur_ = un_ >> 3, us_ = (un_ & 7) ^ (ur_ & 7);                        \
      GLDS16(gs_ + (size_t)ur_ * 11008 + us_ * 8, ld_ + ub_ * 8);             \
    }                                                                         \
  } while (0)

#define KT(t) (kbase + ((t) >= 86 ? (t) - 86 : (t)))

__global__ __launch_bounds__(512, 2) void gemm_down8(
    const u16* __restrict__ Ab, const u16* __restrict__ Wd,
    const u16* __restrict__ td, const float* __restrict__ Bd,
    const int* __restrict__ lidx, const int* __restrict__ layer,
    float* __restrict__ P0, float* __restrict__ P1) {
  constexpr int H = 4096;
  extern __shared__ u16 smem[];
  u16* sA = smem;
  u16* sB = smem + 32768;
  const int tid = threadIdx.x, lane = tid & 63, wid = tid >> 6;
  const int lr = lane & 15, kg = lane >> 4, rx = lr & 7;
  const int wm = wid >> 2, wn = wid & 3;
  const int m0 = blockIdx.x * 256, n0 = blockIdx.y * 256;
  const int kbase = blockIdx.z * 86;
  float* P = blockIdx.z ? P1 : P0;

  f32x4 acc[8][4] = {};
  bf16x8 a0[4][2], a1[4][2], b0[2][2], b1[2][2];

  STAGE_D(0, 0, KT(0)); STAGE_D(0, 1, KT(0)); STAGE_D(0, 2, KT(0)); STAGE_D(0, 3, KT(0));
  STAGE_D(1, 2, KT(1)); STAGE_D(1, 3, KT(1)); STAGE_D(1, 0, KT(1));
  WAIT_VM6(); BAR();

#pragma unroll 1
  for (int u = 0; u < 43; ++u) {
    const int ktA = KT(2 * u + 1);
    const int kt0 = KT(2 * u + 2);
    const int kt1 = KT(2 * u + 3);
    // g1
    RD_A(a0, 0, 0); RD_B(b0, 0, 0);
    STAGE_D(1, 1, ktA);
    BAR(); WAIT_LGKM0();
    MMA_Q(a0, b0, 0, 0);
    BAR();
    // g2
    RD_B(b1, 0, 1);
    BAR(); WAIT_LGKM0();
    MMA_Q(a0, b1, 0, 2);
    BAR();
    // g3
    RD_A(a1, 0, 1);
    STAGE_D(0, 2, kt0);
    BAR(); WAIT_LGKM0();
    MMA_Q(a1, b1, 4, 2);
    BAR();
    // g4
    STAGE_D(0, 3, kt0); STAGE_D(0, 0, kt0);
    BAR();
    MMA_Q(a1, b0, 4, 0);
    WAIT_VM6();
    BAR();
    // g5
    RD_A(a0, 1, 0); RD_B(b0, 1, 0);
    STAGE_D(0, 1, kt0);
    BAR(); WAIT_LGKM0();
    MMA_Q(a0, b0, 0, 0);
    BAR();
    // g6
    RD_B(b1, 1, 1);
    BAR(); WAIT_LGKM0();
    MMA_Q(a0, b1, 0, 2);
    BAR();
    // g7
    RD_A(a1, 1, 1);
    STAGE_D(1, 2, kt1);
    BAR(); WAIT_LGKM0();
    MMA_Q(a1, b1, 4, 2);
    BAR();
    // g8
    STAGE_D(1, 3, kt1); STAGE_D(1, 0, kt1);
    BAR();
    MMA_Q(a1, b0, 4, 0);
    WAIT_VM6();
    BAR();
  }

  if (blockIdx.z == 0) {
    const int li = lidx[m0 >> 9];
    const size_t bbase = ((size_t)layer[0] * 16 + li) * (size_t)H * 16;
    bf16x8 la[8], lb[4];
    const bf16x8 zz = {};
#pragma unroll
    for (int mf = 0; mf < 8; ++mf) {
      int row = m0 + wm * 128 + mf * 16 + lr;
      la[mf] = (kg < 2) ? *(const bf16x8*)&td[(size_t)row * 16 + kg * 8] : zz;
    }
#pragma unroll
    for (int nf = 0; nf < 4; ++nf) {
      int col = n0 + wn * 64 + nf * 16 + lr;
      if (kg < 2) {
        const float* bp = Bd + bbase + (size_t)col * 16 + kg * 8;
        float4 f0 = *(const float4*)bp;
        float4 f1 = *(const float4*)(bp + 4);
        bf16x8 v;
        v[0] = (__bf16)f0.x; v[1] = (__bf16)f0.y; v[2] = (__bf16)f0.z; v[3] = (__bf16)f0.w;
        v[4] = (__bf16)f1.x; v[5] = (__bf16)f1.y; v[6] = (__bf16)f1.z; v[7] = (__bf16)f1.w;
        lb[nf] = v;
      } else lb[nf] = zz;
    }
#pragma unroll
    for (int mf = 0; mf < 8; ++mf)
#pragma unroll
      for (int nf = 0; nf < 4; ++nf)
        acc[mf][nf] = __builtin_amdgcn_mfma_f32_16x16x32_bf16(la[mf], lb[nf], acc[mf][nf], 0, 0, 0);
  }

#pragma unroll
  for (int mf = 0; mf < 8; ++mf)
#pragma unroll
    for (int nf = 0; nf < 4; ++nf)
#pragma unroll
      for (int j = 0; j < 4; ++j) {
        int row = m0 + wm * 128 + mf * 16 + kg * 4 + j;
        int col = n0 + wn * 64 + nf * 16 + lr;
        P[(size_t)row * H + col] = acc[mf][nf][j];
      }
}

// ---------------- combine: out = P0 + P1 ----------------
__global__ __launch_bounds__(256) void combine_down(
    const float4* __restrict__ P0, const float4* __restrict__ P1,
    float4* __restrict__ out) {
  int gid = blockIdx.x * 256 + threadIdx.x;  // 2048*1024 float4s
  float4 p0 = P0[gid], p1 = P1[gid];
  out[gid] = make_float4(p0.x + p1.x, p0.y + p1.y, p0.z + p1.z, p0.w + p1.w);
}

// ---------------- swiglu: g = silu(g) * u (bf16, 8 elems/thread) ----------------
__global__ __launch_bounds__(256) void swiglu_kernel(uint4* __restrict__ g,
                                                     const uint4* __restrict__ u, int n) {
  int i = blockIdx.x * 256 + threadIdx.x, st = gridDim.x * 256;
  for (; i < n; i += st) {
    uint4 gv = g[i], uv = u[i], ov;
    unsigned* gw = (unsigned*)&gv;
    unsigned* uw = (unsigned*)&uv;
    unsigned* ow = (unsigned*)&ov;
#pragma unroll
    for (int q = 0; q < 4; ++q) {
      float g0 = __builtin_bit_cast(float, gw[q] << 16);
      float g1 = __builtin_bit_cast(float, gw[q] & 0xffff0000u);
      float u0 = __builtin_bit_cast(float, uw[q] << 16);
      float u1 = __builtin_bit_cast(float, uw[q] & 0xffff0000u);
      float a0 = g0 / (1.f + __expf(-g0)) * u0;
      float a1 = g1 / (1.f + __expf(-g1)) * u1;
      ow[q] = (unsigned)f2b(a0) | ((unsigned)f2b(a1) << 16);
    }
    g[i] = ov;
  }
}

extern "C" void kernel_launch(void* const* d_in, const int* in_sizes, int n_in,
                              void* d_out, int out_size, void* d_ws, size_t ws_size,
                              hipStream_t stream) {
  const float* x  = (const float*)d_in[0];
  const float* Wg = (const float*)d_in[1];
  const float* Wu = (const float*)d_in[2];
  const float* Wd = (const float*)d_in[3];
  const float* Ag = (const float*)d_in[4];
  const float* Bg = (const float*)d_in[5];
  const float* Au = (const float*)d_in[6];
  const float* Bu = (const float*)d_in[7];
  const float* Ad = (const float*)d_in[8];
  const float* Bd = (const float*)d_in[9];
  const int* lidx = (const int*)d_in[10];
  const int* lay  = (const int*)d_in[11];
  float* out = (float*)d_out;

  // ws layout (bytes). Reuse after gup8+swiglu: wub -> P1, ubuf -> P0.
  // Wd bf16 lives in its own slot (wdb3), written by gup8's tail-cvt blocks.
  char* ws = (char*)d_ws;
  u16*  xb   = (u16*)(ws + 0);            //  16,777,216  x bf16 [2048][4096]
  u16*  wgb  = (u16*)(ws + 16777216);     //  90,177,536  Wg bf16 [11008][4096]
  u16*  wub  = (u16*)(ws + 106954752);    //  90,177,536  Wu bf16
  u16*  gbuf = (u16*)(ws + 197132288);    //  45,088,768  gate -> act bf16 [2048][11008]
  u16*  ubuf = (u16*)(ws + 242221056);    //  45,088,768  up bf16
  u16*  tg   = (u16*)(ws + 287309824);    //  65,536
  u16*  tu   = (u16*)(ws + 287375360);    //  65,536
  u16*  td   = (u16*)(ws + 287440896);    //  65,536
  u16*  wdb3 = (u16*)(ws + 287506432);    //  90,177,536  Wd bf16 (proven in-budget r8)
  float* P0  = (float*)ubuf;              //  33,554,432 fp32 [2048][4096]
  float* P1  = (float*)wub;

  hipFuncSetAttribute(reinterpret_cast<const void*>(gemm_gup8),
                      hipFuncAttributeMaxDynamicSharedMemorySize, 131072);
  hipFuncSetAttribute(reinterpret_cast<const void*>(gemm_down8),
                      hipFuncAttributeMaxDynamicSharedMemorySize, 131072);

  cvt_kernel<<<1024, 256, 0, stream>>>((const float4*)x,  (ushort4*)xb,  8388608 / 4);
  cvt_kernel<<<2048, 256, 0, stream>>>((const float4*)Wg, (ushort4*)wgb, 45088768 / 4);
  cvt_kernel<<<2048, 256, 0, stream>>>((const float4*)Wu, (ushort4*)wub, 45088768 / 4);

  lora_t2<<<128, 256, 0, stream>>>(xb, 4096, Ag, Au, lidx, lay, tg, tu);

  // 704 GEMM blocks + 256 Wd-cvt tail blocks
  gemm_gup8<<<dim3(960), 512, 131072, stream>>>(
      xb, wgb, wub, tg, tu, Bg, Bu, lidx, lay, gbuf, ubuf,
      (const float4*)Wd, (ushort4*)wdb3);

  swiglu_kernel<<<2048, 256, 0, stream>>>((uint4*)gbuf, (const uint4*)ubuf, 2818048);

  lora_t2<<<128, 256, 0, stream>>>(gbuf, 11008, Ad, nullptr, lidx, lay, td, nullptr);

  gemm_down8<<<dim3(8, 16, 2), 512, 131072, stream>>>(gbuf, wdb3, td, Bd, lidx, lay,
                                                      P0, P1);

  combine_down<<<8192, 256, 0, stream>>>((const float4*)P0, (const float4*)P1,
                                         (float4*)out);
}

// Round 14
// 734.044 us; speedup vs baseline: 1.0603x; 1.0603x over previous
//
#include <hip/hip_runtime.h>
#include <hip/hip_bf16.h>

typedef __bf16 bf16x8 __attribute__((ext_vector_type(8)));
typedef float  f32x4  __attribute__((ext_vector_type(4)));
typedef unsigned short u16;

#define GLDS16(gsrc, ldst)                                                        \
  __builtin_amdgcn_global_load_lds(                                               \
      (const __attribute__((address_space(1))) unsigned int*)(gsrc),              \
      (__attribute__((address_space(3))) unsigned int*)(ldst), 16, 0, 0)

#define BAR() __builtin_amdgcn_s_barrier()
#define WAIT_LGKM0() asm volatile("s_waitcnt lgkmcnt(0)" ::: "memory")
#define WAIT_VM4() asm volatile("s_waitcnt vmcnt(4)" ::: "memory")

__device__ __forceinline__ u16 f2b(float f) {
  unsigned int u = __builtin_bit_cast(unsigned int, f);
  u = (u + 0x7fffu + ((u >> 16) & 1u)) >> 16;
  return (u16)u;
}
__device__ __forceinline__ float b2f(u16 b) {
  unsigned int u = ((unsigned int)b) << 16;
  return __builtin_bit_cast(float, u);
}

// ---------------- fp32 -> bf16 convert ----------------
__global__ __launch_bounds__(256) void cvt_kernel(const float4* __restrict__ in,
                                                  ushort4* __restrict__ out, int n4) {
  int i = blockIdx.x * blockDim.x + threadIdx.x;
  int stride = gridDim.x * blockDim.x;
  for (; i < n4; i += stride) {
    float4 v = in[i];
    ushort4 o;
    o.x = f2b(v.x); o.y = f2b(v.y); o.z = f2b(v.z); o.w = f2b(v.w);
    out[i] = o;
  }
}

// ------ LoRA rank-projection, wave-K-split: t_bf16[m][r] = 0.5*sum_k Xb[m][k]*A[r][k]
__global__ __launch_bounds__(256) void lora_t2(const u16* __restrict__ Xb, int K,
                                               const float* __restrict__ A1,
                                               const float* __restrict__ A2,
                                               const int* __restrict__ lidx,
                                               const int* __restrict__ layer,
                                               u16* __restrict__ t1,
                                               u16* __restrict__ t2) {
  __shared__ float red1[4][64][4];
  __shared__ float red2[4][64][4];
  const int lane = threadIdx.x & 63, wid = threadIdx.x >> 6;
  const int m0 = blockIdx.x * 16;
  const int li = lidx[m0 >> 9];
  const size_t abase = ((size_t)layer[0] * 16 + li) * 16 * (size_t)K;
  const int r = lane & 15, kg = lane >> 4;
  const int Kq = K >> 2, kb = wid * Kq;
  f32x4 acc1 = {0.f, 0.f, 0.f, 0.f}, acc2 = {0.f, 0.f, 0.f, 0.f};
  for (int k0 = kb; k0 < kb + Kq; k0 += 32) {
    bf16x8 a = *(const bf16x8*)&Xb[(size_t)(m0 + r) * K + k0 + kg * 8];
    const float* ap = A1 + abase + (size_t)r * K + k0 + kg * 8;
    float4 f0 = *(const float4*)ap;
    float4 f1 = *(const float4*)(ap + 4);
    bf16x8 b;
    b[0] = (__bf16)f0.x; b[1] = (__bf16)f0.y; b[2] = (__bf16)f0.z; b[3] = (__bf16)f0.w;
    b[4] = (__bf16)f1.x; b[5] = (__bf16)f1.y; b[6] = (__bf16)f1.z; b[7] = (__bf16)f1.w;
    acc1 = __builtin_amdgcn_mfma_f32_16x16x32_bf16(a, b, acc1, 0, 0, 0);
    if (A2) {
      const float* ap2 = A2 + abase + (size_t)r * K + k0 + kg * 8;
      float4 g0 = *(const float4*)ap2;
      float4 g1 = *(const float4*)(ap2 + 4);
      bf16x8 b2;
      b2[0] = (__bf16)g0.x; b2[1] = (__bf16)g0.y; b2[2] = (__bf16)g0.z; b2[3] = (__bf16)g0.w;
      b2[4] = (__bf16)g1.x; b2[5] = (__bf16)g1.y; b2[6] = (__bf16)g1.z; b2[7] = (__bf16)g1.w;
      acc2 = __builtin_amdgcn_mfma_f32_16x16x32_bf16(a, b2, acc2, 0, 0, 0);
    }
  }
#pragma unroll
  for (int j = 0; j < 4; ++j) {
    red1[wid][lane][j] = acc1[j];
    if (A2) red2[wid][lane][j] = acc2[j];
  }
  __syncthreads();
  if (wid == 0) {
#pragma unroll
    for (int j = 0; j < 4; ++j) {
      int m = m0 + kg * 4 + j;
      float v1 = red1[0][lane][j] + red1[1][lane][j] + red1[2][lane][j] + red1[3][lane][j];
      t1[(size_t)m * 16 + r] = f2b(0.5f * v1);
      if (A2) {
        float v2 = red2[0][lane][j] + red2[1][lane][j] + red2[2][lane][j] + red2[3][lane][j];
        t2[(size_t)m * 16 + r] = f2b(0.5f * v2);
      }
    }
  }
}

// ===================== shared 8-phase tile macros =====================
#define RD_A(dst, buf, mh) do {                                                \
    _Pragma("unroll")                                                          \
    for (int mf_ = 0; mf_ < 4; ++mf_)                                          \
      _Pragma("unroll")                                                        \
      for (int ks_ = 0; ks_ < 2; ++ks_) {                                      \
        int row_ = wm * 128 + (mh) * 64 + mf_ * 16 + lr;                       \
        int sl_ = (ks_ * 4 + kg) ^ rx;                                         \
        dst[mf_][ks_] = *(const bf16x8*)&sA[(buf) * 16384 + row_ * 64 + sl_ * 8]; \
      }                                                                        \
  } while (0)

#define RD_B(dst, buf, nh) do {                                                \
    _Pragma("unroll")                                                          \
    for (int nf_ = 0; nf_ < 2; ++nf_)                                          \
      _Pragma("unroll")                                                        \
      for (int ks_ = 0; ks_ < 2; ++ks_) {                                      \
        int row_ = wn * 64 + (nh) * 32 + nf_ * 16 + lr;                        \
        int sl_ = (ks_ * 4 + kg) ^ rx;                                         \
        dst[nf_][ks_] = *(const bf16x8*)&sB[(buf) * 16384 + row_ * 64 + sl_ * 8]; \
      }                                                                        \
  } while (0)

// B-read for the fused kernel: 128-row weight tile, per-wave 32 rows.
#define RD_BW(dst, SB, buf) do {                                               \
    _Pragma("unroll")                                                          \
    for (int nf_ = 0; nf_ < 2; ++nf_)                                          \
      _Pragma("unroll")                                                        \
      for (int ks_ = 0; ks_ < 2; ++ks_) {                                      \
        int row_ = wn * 32 + nf_ * 16 + lr;                                    \
        int sl_ = (ks_ * 4 + kg) ^ rx;                                         \
        dst[nf_][ks_] = *(const bf16x8*)&SB[(buf) * 8192 + row_ * 64 + sl_ * 8]; \
      }                                                                        \
  } while (0)

#define MMA_Q(AF, BF, mb, nb) do {                                             \
    __builtin_amdgcn_s_setprio(1);                                             \
    _Pragma("unroll")                                                          \
    for (int mf_ = 0; mf_ < 4; ++mf_)                                          \
      _Pragma("unroll")                                                        \
      for (int nf_ = 0; nf_ < 2; ++nf_)                                        \
        _Pragma("unroll")                                                      \
        for (int ks_ = 0; ks_ < 2; ++ks_)                                      \
          acc[(mb) + mf_][(nb) + nf_] = __builtin_amdgcn_mfma_f32_16x16x32_bf16( \
              AF[mf_][ks_], BF[nf_][ks_], acc[(mb) + mf_][(nb) + nf_], 0, 0, 0); \
    __builtin_amdgcn_s_setprio(0);                                             \
  } while (0)

#define MMA_F(AF, BF, ACC, mb) do {                                            \
    __builtin_amdgcn_s_setprio(1);                                             \
    _Pragma("unroll")                                                          \
    for (int mf_ = 0; mf_ < 4; ++mf_)                                          \
      _Pragma("unroll")                                                        \
      for (int nf_ = 0; nf_ < 2; ++nf_)                                        \
        _Pragma("unroll")                                                      \
        for (int ks_ = 0; ks_ < 2; ++ks_)                                      \
          ACC[(mb) + mf_][nf_] = __builtin_amdgcn_mfma_f32_16x16x32_bf16(      \
              AF[mf_][ks_], BF[nf_][ks_], ACC[(mb) + mf_][nf_], 0, 0, 0);      \
    __builtin_amdgcn_s_setprio(0);                                             \
  } while (0)

// ====== fused gate+up GEMM, tile 256m x 128n, output-stationary SwiGLU =========
// halves: 0 = X rows 0-127, 1 = X rows 128-255, 2 = Wg rows n0..n0+127,
//         3 = Wu rows n0..n0+127. Phase skeleton identical to the proven r11
//         schedule (same stage slots, same vmcnt(4) counting).
#define STAGE_F(buf, half, kt) do {                                            \
    const u16* gs_; u16* ld_;                                                  \
    if ((half) == 0)      { gs_ = Xb + (size_t)m0 * 4096 + (size_t)(kt) * 64;         ld_ = sA  + (buf) * 16384; }        \
    else if ((half) == 1) { gs_ = Xb + (size_t)(m0 + 128) * 4096 + (size_t)(kt) * 64; ld_ = sA  + (buf) * 16384 + 8192; } \
    else if ((half) == 2) { gs_ = Wg + (size_t)n0 * 4096 + (size_t)(kt) * 64;         ld_ = sBG + (buf) * 8192; }         \
    else                  { gs_ = Wu + (size_t)n0 * 4096 + (size_t)(kt) * 64;         ld_ = sBU + (buf) * 8192; }         \
    _Pragma("unroll")                                                          \
    for (int i_ = 0; i_ < 2; ++i_) {                                           \
      int ub_ = (wid << 6) + i_ * 512;                                         \
      int un_ = ub_ + lane;                                                    \
      int ur_ = un_ >> 3, us_ = (un_ & 7) ^ (ur_ & 7);                         \
      GLDS16(gs_ + (size_t)ur_ * 4096 + us_ * 8, ld_ + ub_ * 8);               \
    }                                                                          \
  } while (0)

// Blocks 0..703: fused GEMM (8 m-tiles x 88 padded n-tiles of 128, XCD-grouped).
// Blocks 704..959: convert Wd fp32->bf16 into wdb3 (fills the GEMM tail wave).
__global__ __launch_bounds__(512, 2) void gemm_gup_fused(
    const u16* __restrict__ Xb, const u16* __restrict__ Wg, const u16* __restrict__ Wu,
    const u16* __restrict__ tg, const u16* __restrict__ tu,
    const float* __restrict__ Bg, const float* __restrict__ Bu,
    const int* __restrict__ lidx, const int* __restrict__ layer,
    u16* __restrict__ act,
    const float4* __restrict__ Wdf, ushort4* __restrict__ wdb3) {
  constexpr int F = 11008;
  const int b = blockIdx.x;
  if (b >= 704) {  // Wd convert tail
    int i = (b - 704) * 512 + threadIdx.x;
    for (; i < 11272192; i += 256 * 512) {
      float4 v = Wdf[i];
      ushort4 o;
      o.x = f2b(v.x); o.y = f2b(v.y); o.z = f2b(v.z); o.w = f2b(v.w);
      wdb3[i] = o;
    }
    return;
  }
  const int xcd = b & 7, j = b >> 3;
  const int ny = xcd + 8 * (j >> 3);
  const int mx = j & 7;
  if (ny >= 86) return;
  extern __shared__ u16 smem[];
  u16* sA  = smem;                    // [2][256*64]  64 KB
  u16* sBG = smem + 32768;            // [2][128*64]  32 KB
  u16* sBU = smem + 49152;            // [2][128*64]  32 KB
  const int tid = threadIdx.x, lane = tid & 63, wid = tid >> 6;
  const int lr = lane & 15, kg = lane >> 4, rx = lr & 7;
  const int wm = wid >> 2, wn = wid & 3;
  const int m0 = mx * 256;
  const int n0 = ny * 128;

  f32x4 accg[8][2] = {}, accu[8][2] = {};
  bf16x8 a0[4][2], a1[4][2], bg[2][2], bu[2][2];

  // prologue: tile0 all 4 halves -> buf0; tile1 weights -> buf1
  STAGE_F(0, 0, 0); STAGE_F(0, 1, 0); STAGE_F(0, 2, 0); STAGE_F(0, 3, 0);
  STAGE_F(1, 2, 1); STAGE_F(1, 3, 1);
  WAIT_VM4(); BAR();

#pragma unroll 1
  for (int u = 0; u < 32; ++u) {
    const int ktA = (2 * u + 1) & 63;
    const int kt0 = (2 * u + 2) & 63;
    const int kt1 = (2 * u + 3) & 63;
    // g1
    RD_A(a0, 0, 0); RD_BW(bg, sBG, 0);
    STAGE_F(1, 0, ktA);
    BAR(); WAIT_LGKM0();
    MMA_F(a0, bg, accg, 0);
    BAR();
    // g2
    RD_BW(bu, sBU, 0);
    STAGE_F(1, 1, ktA);
    BAR(); WAIT_LGKM0();
    MMA_F(a0, bu, accu, 0);
    BAR();
    // g3
    RD_A(a1, 0, 1);
    STAGE_F(0, 2, kt0);
    BAR(); WAIT_LGKM0();
    MMA_F(a1, bu, accu, 4);
    BAR();
    // g4
    STAGE_F(0, 3, kt0);
    BAR();
    MMA_F(a1, bg, accg, 4);
    WAIT_VM4();
    BAR();
    // g5
    RD_A(a0, 1, 0); RD_BW(bg, sBG, 1);
    STAGE_F(0, 0, kt0);
    BAR(); WAIT_LGKM0();
    MMA_F(a0, bg, accg, 0);
    BAR();
    // g6
    RD_BW(bu, sBU, 1);
    STAGE_F(0, 1, kt0);
    BAR(); WAIT_LGKM0();
    MMA_F(a0, bu, accu, 0);
    BAR();
    // g7
    RD_A(a1, 1, 1);
    STAGE_F(1, 2, kt1);
    BAR(); WAIT_LGKM0();
    MMA_F(a1, bu, accu, 4);
    BAR();
    // g8
    STAGE_F(1, 3, kt1);
    BAR();
    MMA_F(a1, bg, accg, 4);
    WAIT_VM4();
    BAR();
  }

  // ---- LoRA via MFMA (gate, then up; regs reused), then silu(g)*u store ----
  const int li = lidx[m0 >> 9];
  const size_t bbase = ((size_t)layer[0] * 16 + li) * (size_t)F * 16;
  bf16x8 la[8], lb[2];
  const bf16x8 zz = {};
  // gate
#pragma unroll
  for (int mf = 0; mf < 8; ++mf) {
    int row = m0 + wm * 128 + mf * 16 + lr;
    la[mf] = (kg < 2) ? *(const bf16x8*)&tg[(size_t)row * 16 + kg * 8] : zz;
  }
#pragma unroll
  for (int nf = 0; nf < 2; ++nf) {
    int col = n0 + wn * 32 + nf * 16 + lr;
    if (kg < 2) {
      const float* bp = Bg + bbase + (size_t)col * 16 + kg * 8;
      float4 f0 = *(const float4*)bp;
      float4 f1 = *(const float4*)(bp + 4);
      bf16x8 v;
      v[0] = (__bf16)f0.x; v[1] = (__bf16)f0.y; v[2] = (__bf16)f0.z; v[3] = (__bf16)f0.w;
      v[4] = (__bf16)f1.x; v[5] = (__bf16)f1.y; v[6] = (__bf16)f1.z; v[7] = (__bf16)f1.w;
      lb[nf] = v;
    } else lb[nf] = zz;
  }
#pragma unroll
  for (int mf = 0; mf < 8; ++mf)
#pragma unroll
    for (int nf = 0; nf < 2; ++nf)
      accg[mf][nf] = __builtin_amdgcn_mfma_f32_16x16x32_bf16(la[mf], lb[nf], accg[mf][nf], 0, 0, 0);
  // up
#pragma unroll
  for (int mf = 0; mf < 8; ++mf) {
    int row = m0 + wm * 128 + mf * 16 + lr;
    la[mf] = (kg < 2) ? *(const bf16x8*)&tu[(size_t)row * 16 + kg * 8] : zz;
  }
#pragma unroll
  for (int nf = 0; nf < 2; ++nf) {
    int col = n0 + wn * 32 + nf * 16 + lr;
    if (kg < 2) {
      const float* bp = Bu + bbase + (size_t)col * 16 + kg * 8;
      float4 f0 = *(const float4*)bp;
      float4 f1 = *(const float4*)(bp + 4);
      bf16x8 v;
      v[0] = (__bf16)f0.x; v[1] = (__bf16)f0.y; v[2] = (__bf16)f0.z; v[3] = (__bf16)f0.w;
      v[4] = (__bf16)f1.x; v[5] = (__bf16)f1.y; v[6] = (__bf16)f1.z; v[7] = (__bf16)f1.w;
      lb[nf] = v;
    } else lb[nf] = zz;
  }
#pragma unroll
  for (int mf = 0; mf < 8; ++mf)
#pragma unroll
    for (int nf = 0; nf < 2; ++nf)
      accu[mf][nf] = __builtin_amdgcn_mfma_f32_16x16x32_bf16(la[mf], lb[nf], accu[mf][nf], 0, 0, 0);

#pragma unroll
  for (int mf = 0; mf < 8; ++mf)
#pragma unroll
    for (int nf = 0; nf < 2; ++nf)
#pragma unroll
      for (int j2 = 0; j2 < 4; ++j2) {
        int row = m0 + wm * 128 + mf * 16 + kg * 4 + j2;
        int col = n0 + wn * 32 + nf * 16 + lr;
        float g = accg[mf][nf][j2], uu = accu[mf][nf][j2];
        float s = g / (1.f + __expf(-g));
        act[(size_t)row * F + col] = f2b(s * uu);
      }
}

// ====== 8-phase 256x256 down GEMM, K-split=2 over 172 tiles, fp32 partials =====
#define STAGE_D(buf, half, kt) do {                                           \
    int r0_ = ((half) & 1) * 128;                                             \
    const u16* gs_ = ((half) < 2)                                             \
        ? (Ab + (size_t)(m0 + r0_) * 11008 + (size_t)(kt) * 64)               \
        : (Wd + (size_t)(n0 + r0_) * 11008 + (size_t)(kt) * 64);              \
    u16* ld_ = (((half) < 2) ? sA : sB) + (buf) * 16384 + r0_ * 64;           \
    _Pragma("unroll")                                                         \
    for (int i_ = 0; i_ < 2; ++i_) {                                          \
      int ub_ = (wid << 6) + i_ * 512;                                        \
      int un_ = ub_ + lane;                                                   \
      int ur_ = un_ >> 3, us_ = (un_ & 7) ^ (ur_ & 7);                        \
      GLDS16(gs_ + (size_t)ur_ * 11008 + us_ * 8, ld_ + ub_ * 8);             \
    }                                                                         \
  } while (0)

#define KT(t) (kbase + ((t) >= 86 ? (t) - 86 : (t)))

__global__ __launch_bounds__(512, 2) void gemm_down8(
    const u16* __restrict__ Ab, const u16* __restrict__ Wd,
    const u16* __restrict__ td, const float* __restrict__ Bd,
    const int* __restrict__ lidx, const int* __restrict__ layer,
    float* __restrict__ P0, float* __restrict__ P1) {
  constexpr int H = 4096;
  extern __shared__ u16 smem[];
  u16* sA = smem;
  u16* sB = smem + 32768;
  const int tid = threadIdx.x, lane = tid & 63, wid = tid >> 6;
  const int lr = lane & 15, kg = lane >> 4, rx = lr & 7;
  const int wm = wid >> 2, wn = wid & 3;
  const int m0 = blockIdx.x * 256, n0 = blockIdx.y * 256;
  const int kbase = blockIdx.z * 86;
  float* P = blockIdx.z ? P1 : P0;

  f32x4 acc[8][4] = {};
  bf16x8 a0[4][2], a1[4][2], b0[2][2], b1[2][2];

  STAGE_D(0, 0, KT(0)); STAGE_D(0, 1, KT(0)); STAGE_D(0, 2, KT(0)); STAGE_D(0, 3, KT(0));
  STAGE_D(1, 2, KT(1)); STAGE_D(1, 3, KT(1));
  WAIT_VM4(); BAR();

#pragma unroll 1
  for (int u = 0; u < 43; ++u) {
    const int ktA = KT(2 * u + 1);
    const int kt0 = KT(2 * u + 2);
    const int kt1 = KT(2 * u + 3);
    RD_A(a0, 0, 0); RD_B(b0, 0, 0);
    STAGE_D(1, 0, ktA);
    BAR(); WAIT_LGKM0();
    MMA_Q(a0, b0, 0, 0);
    BAR();
    RD_B(b1, 0, 1);
    STAGE_D(1, 1, ktA);
    BAR(); WAIT_LGKM0();
    MMA_Q(a0, b1, 0, 2);
    BAR();
    RD_A(a1, 0, 1);
    STAGE_D(0, 2, kt0);
    BAR(); WAIT_LGKM0();
    MMA_Q(a1, b1, 4, 2);
    BAR();
    STAGE_D(0, 3, kt0);
    BAR();
    MMA_Q(a1, b0, 4, 0);
    WAIT_VM4();
    BAR();
    RD_A(a0, 1, 0); RD_B(b0, 1, 0);
    STAGE_D(0, 0, kt0);
    BAR(); WAIT_LGKM0();
    MMA_Q(a0, b0, 0, 0);
    BAR();
    RD_B(b1, 1, 1);
    STAGE_D(0, 1, kt0);
    BAR(); WAIT_LGKM0();
    MMA_Q(a0, b1, 0, 2);
    BAR();
    RD_A(a1, 1, 1);
    STAGE_D(1, 2, kt1);
    BAR(); WAIT_LGKM0();
    MMA_Q(a1, b1, 4, 2);
    BAR();
    STAGE_D(1, 3, kt1);
    BAR();
    MMA_Q(a1, b0, 4, 0);
    WAIT_VM4();
    BAR();
  }

  if (blockIdx.z == 0) {
    const int li = lidx[m0 >> 9];
    const size_t bbase = ((size_t)layer[0] * 16 + li) * (size_t)H * 16;
    bf16x8 la[8], lb[4];
    const bf16x8 zz = {};
#pragma unroll
    for (int mf = 0; mf < 8; ++mf) {
      int row = m0 + wm * 128 + mf * 16 + lr;
      la[mf] = (kg < 2) ? *(const bf16x8*)&td[(size_t)row * 16 + kg * 8] : zz;
    }
#pragma unroll
    for (int nf = 0; nf < 4; ++nf) {
      int col = n0 + wn * 64 + nf * 16 + lr;
      if (kg < 2) {
        const float* bp = Bd + bbase + (size_t)col * 16 + kg * 8;
        float4 f0 = *(const float4*)bp;
        float4 f1 = *(const float4*)(bp + 4);
        bf16x8 v;
        v[0] = (__bf16)f0.x; v[1] = (__bf16)f0.y; v[2] = (__bf16)f0.z; v[3] = (__bf16)f0.w;
        v[4] = (__bf16)f1.x; v[5] = (__bf16)f1.y; v[6] = (__bf16)f1.z; v[7] = (__bf16)f1.w;
        lb[nf] = v;
      } else lb[nf] = zz;
    }
#pragma unroll
    for (int mf = 0; mf < 8; ++mf)
#pragma unroll
      for (int nf = 0; nf < 4; ++nf)
        acc[mf][nf] = __builtin_amdgcn_mfma_f32_16x16x32_bf16(la[mf], lb[nf], acc[mf][nf], 0, 0, 0);
  }

#pragma unroll
  for (int mf = 0; mf < 8; ++mf)
#pragma unroll
    for (int nf = 0; nf < 4; ++nf)
#pragma unroll
      for (int j = 0; j < 4; ++j) {
        int row = m0 + wm * 128 + mf * 16 + kg * 4 + j;
        int col = n0 + wn * 64 + nf * 16 + lr;
        P[(size_t)row * H + col] = acc[mf][nf][j];
      }
}

// ---------------- combine: out = P0 + P1 ----------------
__global__ __launch_bounds__(256) void combine_down(
    const float4* __restrict__ P0, const float4* __restrict__ P1,
    float4* __restrict__ out) {
  int gid = blockIdx.x * 256 + threadIdx.x;
  float4 p0 = P0[gid], p1 = P1[gid];
  out[gid] = make_float4(p0.x + p1.x, p0.y + p1.y, p0.z + p1.z, p0.w + p1.w);
}

extern "C" void kernel_launch(void* const* d_in, const int* in_sizes, int n_in,
                              void* d_out, int out_size, void* d_ws, size_t ws_size,
                              hipStream_t stream) {
  const float* x  = (const float*)d_in[0];
  const float* Wg = (const float*)d_in[1];
  const float* Wu = (const float*)d_in[2];
  const float* Wd = (const float*)d_in[3];
  const float* Ag = (const float*)d_in[4];
  const float* Bg = (const float*)d_in[5];
  const float* Au = (const float*)d_in[6];
  const float* Bu = (const float*)d_in[7];
  const float* Ad = (const float*)d_in[8];
  const float* Bd = (const float*)d_in[9];
  const int* lidx = (const int*)d_in[10];
  const int* lay  = (const int*)d_in[11];
  float* out = (float*)d_out;

  char* ws = (char*)d_ws;
  u16*  xb   = (u16*)(ws + 0);            //  16,777,216  x bf16 [2048][4096]
  u16*  wgb  = (u16*)(ws + 16777216);     //  90,177,536  Wg bf16 [11008][4096]
  u16*  wub  = (u16*)(ws + 106954752);    //  90,177,536  Wu bf16
  u16*  gbuf = (u16*)(ws + 197132288);    //  45,088,768  act bf16 [2048][11008]
  u16*  tg   = (u16*)(ws + 287309824);    //  65,536
  u16*  tu   = (u16*)(ws + 287375360);    //  65,536
  u16*  td   = (u16*)(ws + 287440896);    //  65,536
  u16*  wdb3 = (u16*)(ws + 287506432);    //  90,177,536  Wd bf16
  float* P0  = (float*)(ws + 242221056);  //  33,554,432 fp32 (old ubuf slot)
  float* P1  = (float*)wub;

  hipFuncSetAttribute(reinterpret_cast<const void*>(gemm_gup_fused),
                      hipFuncAttributeMaxDynamicSharedMemorySize, 131072);
  hipFuncSetAttribute(reinterpret_cast<const void*>(gemm_down8),
                      hipFuncAttributeMaxDynamicSharedMemorySize, 131072);

  cvt_kernel<<<1024, 256, 0, stream>>>((const float4*)x,  (ushort4*)xb,  8388608 / 4);
  cvt_kernel<<<2048, 256, 0, stream>>>((const float4*)Wg, (ushort4*)wgb, 45088768 / 4);
  cvt_kernel<<<2048, 256, 0, stream>>>((const float4*)Wu, (ushort4*)wub, 45088768 / 4);

  lora_t2<<<128, 256, 0, stream>>>(xb, 4096, Ag, Au, lidx, lay, tg, tu);

  // 704 fused GEMM blocks + 256 Wd-cvt tail blocks
  gemm_gup_fused<<<dim3(960), 512, 131072, stream>>>(
      xb, wgb, wub, tg, tu, Bg, Bu, lidx, lay, gbuf,
      (const float4*)Wd, (ushort4*)wdb3);

  lora_t2<<<128, 256, 0, stream>>>(gbuf, 11008, Ad, nullptr, lidx, lay, td, nullptr);

  gemm_down8<<<dim3(8, 16, 2), 512, 131072, stream>>>(gbuf, wdb3, td, Bd, lidx, lay,
                                                      P0, P1);

  combine_down<<<8192, 256, 0, stream>>>((const float4*)P0, (const float4*)P1,
                                         (float4*)out);
}